// Round 17
// baseline (135.611 us; speedup 1.0000x reference)
//
#include <hip/hip_runtime.h>
#include <math.h>

#define BB 32
#define NN 64
#define PP 4
#define HH 300

#define NKK 10    // edge reduction tiles: ceil(300/32)
#define NCT 19    // node output col-tiles of 16: ceil(300/16)
#define NCTE 20   // edge col-tiles PADDED to even (tile 19 = zeros)
#define NPAIR 10  // edge ct-pair iterations
#define NKK2 38   // node reduction tiles: ceil(1200/32)
#define CHK 10    // node kk chunk size (4 chunks cover 38)

#define NODE_BLOCKS (BB * 4)          // 128  (4 per b)
#define EDGE_BLOCKS (BB * NN / 2)     // 1024 (32 m-pairs per b)
#define BLOCKS_PER_B 36               // 4 node + 32 edge
#define NTILES (NKK * NCTE + NKK2 * NCT)   // 200 + 722 = 922 wprep tiles

typedef float    f32x4 __attribute__((ext_vector_type(4)));
typedef _Float16 f16x8 __attribute__((ext_vector_type(8)));

__device__ __forceinline__ float eluf(float x) {
    return x > 0.0f ? x : (__expf(x) - 1.0f);
}

// ---------------------------------------------------------------------------
// Merged W-prep, 256-thread blocks (4 tiles/block; was 922 x 64-thread
// blocks — launch-tail trim). Tile (kk, ct): lane l, elem j holds W[h][k],
// h = kk*32 + (l>>4)*8 + j, k = ct*16 + (l&15); zero-padded outside range.
// ---------------------------------------------------------------------------
extern "C" __global__ __launch_bounds__(256)
void wprep_kernel(const float* __restrict__ w_edge,
                  const float* __restrict__ w_np,
                  _Float16* __restrict__ w_hi,
                  _Float16* __restrict__ w2_hi)
{
    const int lane = (int)threadIdx.x & 63;
    int tile = (int)blockIdx.x * 4 + ((int)threadIdx.x >> 6);
    if (tile >= NTILES) return;
    if (tile < NKK * NCTE) {
        const int kk = tile / NCTE, ct = tile % NCTE;
        const int h0 = kk * 32 + (lane >> 4) * 8;
        const int k  = ct * 16 + (lane & 15);
        const size_t base = ((size_t)tile * 64 + lane) * 8;
#pragma unroll
        for (int j = 0; j < 8; ++j) {
            int h = h0 + j;
            float v = (h < HH && k < HH) ? w_edge[h * HH + k] : 0.f;
            w_hi[base + j] = (_Float16)v;
        }
    } else {
        tile -= NKK * NCTE;
        const int kk = tile / NCT, ct = tile % NCT;
        const int h0 = kk * 32 + (lane >> 4) * 8;
        const int k  = ct * 16 + (lane & 15);
        const size_t base = ((size_t)tile * 64 + lane) * 8;
#pragma unroll
        for (int j = 0; j < 8; ++j) {
            int h = h0 + j;
            float v = (h < PP * HH && k < HH) ? w_np[(size_t)h * HH + k] : 0.f;
            w2_hi[base + j] = (_Float16)v;
        }
    }
}

// ---------------------------------------------------------------------------
// FUSED edge + node + final. Edge body = round 12/15 (best, 82.3us total);
// node body = round 10. ROUND-17: final softmax+blend folded in — each
// block publishes its logits with device-scope RELEASE atomics (cross-XCD
// visibility, G16), bumps a per-b completion counter; the 36th block for
// b runs the 64-lane softmax+blend. Counters zeroed per call by
// hipMemsetAsync (graph-capture legal).
// ---------------------------------------------------------------------------
extern "C" __global__ __launch_bounds__(256)
void fused_kernel(const float* __restrict__ edge_attr,
                  const float* __restrict__ node_attr,
                  const float* __restrict__ instr,
                  const float* __restrict__ dist,
                  const float* __restrict__ sim,
                  const float* __restrict__ node_mask,
                  const _Float16* __restrict__ w_hi,
                  const _Float16* __restrict__ w2_hi,
                  const float* __restrict__ w_rel,
                  const float* __restrict__ w_state,
                  const float* __restrict__ rel_sim,
                  float* __restrict__ rel_logits,
                  float* __restrict__ state_logits,
                  int* __restrict__ cnt,
                  float* __restrict__ out)
{
    __shared__ __align__(16) _Float16 Bs[2 * NKK * 512];  // edge: one ct-pair
    __shared__ float redE[2][NN];
    __shared__ float redN[4][16];
    __shared__ int lastFlag;
    const int tid  = (int)threadIdx.x;
    const int wv   = tid >> 6;
    const int lane = tid & 63;
    const int lrow = lane & 15;
    const int lgrp = lane >> 4;
    int bfin;   // batch index this block contributes to

    if ((int)blockIdx.x < NODE_BLOCKS) {
        // =================== NODE PATH (round-10 body) ====================
        const int bid = (int)blockIdx.x;
        const int b   = bid >> 2;
        const int nt  = bid & 3;
        bfin = b;

        const float* arow = node_attr
            + (size_t)(b * NN + nt * 16 + lrow) * (PP * HH);
        float sm[PP];
#pragma unroll
        for (int p = 0; p < PP; ++p) sm[p] = sim[b * PP + p];

        const f16x8* WH = reinterpret_cast<const f16x8*>(w2_hi);

        f32x4 acc[5] = {{0.f,0.f,0.f,0.f},{0.f,0.f,0.f,0.f},{0.f,0.f,0.f,0.f},
                        {0.f,0.f,0.f,0.f},{0.f,0.f,0.f,0.f}};

#pragma unroll 1
        for (int ch = 0; ch < 4; ++ch) {
            f16x8 a_h[CHK];
#pragma unroll
            for (int q = 0; q < CHK; ++q) {
                const int kk = ch * CHK + q;
                const int h0 = kk * 32 + lgrp * 8;
                float v[8];
                if (kk < NKK2 && h0 + 7 < PP * HH) {
                    f32x4 p0 = *reinterpret_cast<const f32x4*>(arow + h0);
                    f32x4 p1 = *reinterpret_cast<const f32x4*>(arow + h0 + 4);
                    v[0] = p0[0]; v[1] = p0[1]; v[2] = p0[2]; v[3] = p0[3];
                    v[4] = p1[0]; v[5] = p1[1]; v[6] = p1[2]; v[7] = p1[3];
                } else {
#pragma unroll
                    for (int j = 0; j < 8; ++j)
                        v[j] = (kk < NKK2 && h0 + j < PP * HH) ? arow[h0 + j] : 0.f;
                }
#pragma unroll
                for (int j = 0; j < 8; ++j) {
                    const int h = h0 + j;
                    const int p = (h < PP * HH) ? (h / HH) : 0;
                    a_h[q][j] = (_Float16)(v[j] * sm[p]);
                }
            }
#pragma unroll
            for (int q = 0; q < CHK; ++q) {
                const int kk = ch * CHK + q;
                if (kk < NKK2) {
#pragma unroll
                    for (int c = 0; c < 5; ++c) {
                        const int ct = wv + 4 * c;
                        if (ct < NCT) {
                            f16x8 bh = WH[(kk * NCT + ct) * 64 + lane];
                            acc[c] = __builtin_amdgcn_mfma_f32_16x16x32_f16(a_h[q], bh, acc[c], 0, 0, 0);
                        }
                    }
                }
            }
        }

        float rs0 = 0.f, rs1 = 0.f, rs2 = 0.f, rs3 = 0.f;
#pragma unroll
        for (int c = 0; c < 5; ++c) {
            const int ct = wv + 4 * c;
            if (ct < NCT) {
                const int k  = ct * 16 + lrow;
                const bool ok = k < HH;
                const int kc = ok ? k : (HH - 1);
                const float iv  = instr[b * HH + kc];
                const float wsv = ok ? w_state[kc] : 0.f;
                rs0 += eluf(acc[c][0] * iv) * wsv;
                rs1 += eluf(acc[c][1] * iv) * wsv;
                rs2 += eluf(acc[c][2] * iv) * wsv;
                rs3 += eluf(acc[c][3] * iv) * wsv;
            }
        }
#pragma unroll
        for (int msk = 1; msk < 16; msk <<= 1) {
            rs0 += __shfl_xor(rs0, msk);
            rs1 += __shfl_xor(rs1, msk);
            rs2 += __shfl_xor(rs2, msk);
            rs3 += __shfl_xor(rs3, msk);
        }
        if (lrow == 0) {
            redN[wv][lgrp * 4 + 0] = rs0;
            redN[wv][lgrp * 4 + 1] = rs1;
            redN[wv][lgrp * 4 + 2] = rs2;
            redN[wv][lgrp * 4 + 3] = rs3;
        }
        __syncthreads();
        if (tid < 16) {
            const int n = nt * 16 + tid;
            float v = redN[0][tid] + redN[1][tid] + redN[2][tid] + redN[3][tid]
                      + node_mask[b * NN + n];
            __hip_atomic_store(&state_logits[b * NN + n], v,
                               __ATOMIC_RELEASE, __HIP_MEMORY_SCOPE_AGENT);
        }
    } else {
        // ===================== EDGE PATH (round-12/15 body) ===============
        const int ebid = (int)blockIdx.x - NODE_BLOCKS;
        const int b    = ebid / (NN / 2);
        const int mp   = ebid % (NN / 2);
        const int m0   = 2 * mp;
        const int mi   = wv >> 1;         // which m of the pair
        const int rh   = wv & 1;          // row-half (32 rows) within that m
        bfin = b;

        // ---- A fragments (fp16) for TWO 16-row sets, read-once ----
        const float* abase = edge_attr
            + (size_t)((b * NN + m0 + mi) * NN + rh * 32 + lrow) * HH;
        f16x8 aA[NKK], aB[NKK];
#pragma unroll
        for (int s = 0; s < 2; ++s) {
            const float* arow = abase + (size_t)(s * 16) * HH;
#pragma unroll
            for (int kk = 0; kk < NKK; ++kk) {
                const int h0 = kk * 32 + lgrp * 8;
                float v[8];
                if (h0 + 7 < HH) {
                    f32x4 p0 = *reinterpret_cast<const f32x4*>(arow + h0);
                    f32x4 p1 = *reinterpret_cast<const f32x4*>(arow + h0 + 4);
                    v[0] = p0[0]; v[1] = p0[1]; v[2] = p0[2]; v[3] = p0[3];
                    v[4] = p1[0]; v[5] = p1[1]; v[6] = p1[2]; v[7] = p1[3];
                } else {
#pragma unroll
                    for (int j = 0; j < 8; ++j)
                        v[j] = (h0 + j < HH) ? arow[h0 + j] : 0.f;
                }
                if (s == 0) {
#pragma unroll
                    for (int j = 0; j < 8; ++j) aA[kk][j] = (_Float16)v[j];
                } else {
#pragma unroll
                    for (int j = 0; j < 8; ++j) aB[kk][j] = (_Float16)v[j];
                }
            }
        }

        const f16x8* WH = reinterpret_cast<const f16x8*>(w_hi);
        const int binst = b * HH;

        // ---- staging ownership: 20 pair-tiles over 4 waves (5 each) ----
        const int t0 = wv * 5;
        const f16x8* gp[5];
        int ldst[5];
#pragma unroll
        for (int i = 0; i < 5; ++i) {
            int t  = t0 + i;
            int c  = (t >= NKK) ? 1 : 0;
            int kk = t - c * NKK;
            gp[i]   = WH + ((size_t)kk * NCTE + c) * 64 + lane;
            ldst[i] = (c * NKK + kk) * 512 + lane * 8;
        }

        f16x8 st[5];
#pragma unroll
        for (int i = 0; i < 5; ++i) { st[i] = gp[i][0]; gp[i] += 128; }

        float rsA0 = 0.f, rsA1 = 0.f, rsA2 = 0.f, rsA3 = 0.f;
        float rsB0 = 0.f, rsB1 = 0.f, rsB2 = 0.f, rsB3 = 0.f;

#pragma unroll 1
        for (int p = 0; p < NPAIR; ++p) {
#pragma unroll
            for (int i = 0; i < 5; ++i)
                *reinterpret_cast<f16x8*>(&Bs[ldst[i]]) = st[i];
            __syncthreads();

            if (p + 1 < NPAIR) {
#pragma unroll
                for (int i = 0; i < 5; ++i) { st[i] = gp[i][0]; gp[i] += 128; }
            }

            f32x4 accA0 = {0.f, 0.f, 0.f, 0.f};
            f32x4 accA1 = {0.f, 0.f, 0.f, 0.f};
            f32x4 accB0 = {0.f, 0.f, 0.f, 0.f};
            f32x4 accB1 = {0.f, 0.f, 0.f, 0.f};
            const _Float16* bsc = &Bs[lane * 8];
#pragma unroll
            for (int kk = 0; kk < NKK; ++kk) {
                f16x8 b0 = *reinterpret_cast<const f16x8*>(bsc + kk * 512);
                f16x8 b1 = *reinterpret_cast<const f16x8*>(bsc + (NKK + kk) * 512);
                accA0 = __builtin_amdgcn_mfma_f32_16x16x32_f16(aA[kk], b0, accA0, 0, 0, 0);
                accB0 = __builtin_amdgcn_mfma_f32_16x16x32_f16(aB[kk], b0, accB0, 0, 0, 0);
                accA1 = __builtin_amdgcn_mfma_f32_16x16x32_f16(aA[kk], b1, accA1, 0, 0, 0);
                accB1 = __builtin_amdgcn_mfma_f32_16x16x32_f16(aB[kk], b1, accB1, 0, 0, 0);
            }

#pragma unroll
            for (int c = 0; c < 2; ++c) {
                const int k  = (2 * p + c) * 16 + lrow;
                const bool ok = k < HH;
                const int kc = ok ? k : (HH - 1);
                const float iv = instr[binst + kc];
                const float wr = ok ? w_rel[kc] : 0.f;
                const f32x4 aAc = c ? accA1 : accA0;
                const f32x4 aBc = c ? accB1 : accB0;
                rsA0 += eluf(aAc[0] * iv) * wr;
                rsA1 += eluf(aAc[1] * iv) * wr;
                rsA2 += eluf(aAc[2] * iv) * wr;
                rsA3 += eluf(aAc[3] * iv) * wr;
                rsB0 += eluf(aBc[0] * iv) * wr;
                rsB1 += eluf(aBc[1] * iv) * wr;
                rsB2 += eluf(aBc[2] * iv) * wr;
                rsB3 += eluf(aBc[3] * iv) * wr;
            }

            __syncthreads();
        }

#pragma unroll
        for (int msk = 1; msk < 16; msk <<= 1) {
            rsA0 += __shfl_xor(rsA0, msk);
            rsA1 += __shfl_xor(rsA1, msk);
            rsA2 += __shfl_xor(rsA2, msk);
            rsA3 += __shfl_xor(rsA3, msk);
            rsB0 += __shfl_xor(rsB0, msk);
            rsB1 += __shfl_xor(rsB1, msk);
            rsB2 += __shfl_xor(rsB2, msk);
            rsB3 += __shfl_xor(rsB3, msk);
        }
        if (lrow == 0) {
            const int r0 = rh * 32 + lgrp * 4;
            redE[mi][r0 + 0]      = rsA0;
            redE[mi][r0 + 1]      = rsA1;
            redE[mi][r0 + 2]      = rsA2;
            redE[mi][r0 + 3]      = rsA3;
            redE[mi][r0 + 16 + 0] = rsB0;
            redE[mi][r0 + 16 + 1] = rsB1;
            redE[mi][r0 + 16 + 2] = rsB2;
            redE[mi][r0 + 16 + 3] = rsB3;
        }
        __syncthreads();
        if (tid < 128) {
            const int mm = tid >> 6;
            const int ln = tid & 63;
            float v = redE[mm][ln] * dist[b * NN + ln];
#pragma unroll
            for (int msk = 1; msk < 64; msk <<= 1) v += __shfl_xor(v, msk);
            if (ln == 0) {
                float lv = v + node_mask[b * NN + m0 + mm];
                __hip_atomic_store(&rel_logits[b * NN + m0 + mm], lv,
                                   __ATOMIC_RELEASE, __HIP_MEMORY_SCOPE_AGENT);
            }
        }
    }

    // ============ completion count + in-kernel final (last block) =========
    if (tid == 0) {
        int old = __hip_atomic_fetch_add(&cnt[bfin], 1,
                                         __ATOMIC_ACQ_REL,
                                         __HIP_MEMORY_SCOPE_AGENT);
        lastFlag = (old == BLOCKS_PER_B - 1) ? 1 : 0;
    }
    __syncthreads();
    if (lastFlag && tid < 64) {
        const int n = tid;
        float sl = __hip_atomic_load(&state_logits[bfin * NN + n],
                                     __ATOMIC_ACQUIRE, __HIP_MEMORY_SCOPE_AGENT);
        float rl = __hip_atomic_load(&rel_logits[bfin * NN + n],
                                     __ATOMIC_ACQUIRE, __HIP_MEMORY_SCOPE_AGENT);
        float ms = sl, mr = rl;
#pragma unroll
        for (int msk = 1; msk < 64; msk <<= 1) {
            ms = fmaxf(ms, __shfl_xor(ms, msk));
            mr = fmaxf(mr, __shfl_xor(mr, msk));
        }
        float es = __expf(sl - ms);
        float er = __expf(rl - mr);
        float ss = es, sr = er;
#pragma unroll
        for (int msk = 1; msk < 64; msk <<= 1) {
            ss += __shfl_xor(ss, msk);
            sr += __shfl_xor(sr, msk);
        }
        float rr = rel_sim[bfin];
        out[bfin * NN + n] = rr * (er / sr) + (1.f - rr) * (es / ss);
    }
}

extern "C" void kernel_launch(void* const* d_in, const int* in_sizes, int n_in,
                              void* d_out, int out_size, void* d_ws, size_t ws_size,
                              hipStream_t stream) {
    const float* node_attr    = (const float*)d_in[0];
    const float* edge_attr    = (const float*)d_in[1];
    const float* instruction  = (const float*)d_in[2];
    const float* distribution = (const float*)d_in[3];
    const float* node_sim     = (const float*)d_in[4];
    const float* rel_sim      = (const float*)d_in[5];
    const float* node_mask    = (const float*)d_in[6];
    const float* w_np         = (const float*)d_in[7];
    const float* w_edge       = (const float*)d_in[8];
    const float* w_state      = (const float*)d_in[9];
    const float* w_rel        = (const float*)d_in[10];
    float* out = (float*)d_out;

    // workspace layout
    char*  wsb      = (char*)d_ws;
    float* rel_ws   = (float*)wsb;                      // [2048] f32
    float* state_ws = rel_ws + BB * NN;                 // [2048] f32
    int*   cnt      = (int*)(wsb + 16384);              // [32] counters
    const size_t edge_frag = (size_t)NKK * NCTE * 64 * 8 * 2;  // 204,800 B
    _Float16* w_hi  = (_Float16*)(wsb + 16640);
    _Float16* w2_hi = (_Float16*)(wsb + 16640 + edge_frag);

    hipMemsetAsync(cnt, 0, BB * sizeof(int), stream);

    wprep_kernel<<<dim3((NTILES + 3) / 4), dim3(256), 0, stream>>>(
        w_edge, w_np, w_hi, w2_hi);

    fused_kernel<<<dim3(NODE_BLOCKS + EDGE_BLOCKS), dim3(256), 0, stream>>>(
        edge_attr, node_attr, instruction, distribution, node_sim, node_mask,
        w_hi, w2_hi, w_rel, w_state, rel_sim, rel_ws, state_ws, cnt, out);
}

// Round 18
// 82.098 us; speedup vs baseline: 1.6518x; 1.6518x over previous
//
#include <hip/hip_runtime.h>
#include <math.h>

#define BB 32
#define NN 64
#define PP 4
#define HH 300

#define NKK 10    // edge reduction tiles: ceil(300/32)
#define NCT 19    // node output col-tiles of 16: ceil(300/16)
#define NCTE 20   // edge col-tiles PADDED to even (tile 19 = zeros)
#define NPAIR 10  // edge ct-pair iterations
#define NKK2 38   // node reduction tiles: ceil(1200/32)
#define CHK 10    // node kk chunk size (4 chunks cover 38)

#define NODE_BLOCKS (BB * 4)          // 128
#define EDGE_BLOCKS (BB * NN / 2)     // 1024
#define NTILES (NKK * NCTE + NKK2 * NCT)   // 200 + 722 = 922 wprep tiles

typedef float    f32x4 __attribute__((ext_vector_type(4)));
typedef _Float16 f16x8 __attribute__((ext_vector_type(8)));

__device__ __forceinline__ float eluf(float x) {
    return x > 0.0f ? x : (__expf(x) - 1.0f);
}

// ---------------------------------------------------------------------------
// Merged W-prep, 256-thread blocks (4 tiles/block — launch-tail trim vs
// 922 x 64-thread blocks; per-tile math unchanged).
// Tile (kk, ct): lane l, elem j holds W[h][k], h = kk*32 + (l>>4)*8 + j,
// k = ct*16 + (l&15); zero-padded outside valid range.
// ---------------------------------------------------------------------------
extern "C" __global__ __launch_bounds__(256)
void wprep_kernel(const float* __restrict__ w_edge,
                  const float* __restrict__ w_np,
                  _Float16* __restrict__ w_hi,
                  _Float16* __restrict__ w2_hi)
{
    const int lane = (int)threadIdx.x & 63;
    int tile = (int)blockIdx.x * 4 + ((int)threadIdx.x >> 6);
    if (tile >= NTILES) return;
    if (tile < NKK * NCTE) {
        const int kk = tile / NCTE, ct = tile % NCTE;
        const int h0 = kk * 32 + (lane >> 4) * 8;
        const int k  = ct * 16 + (lane & 15);
        const size_t base = ((size_t)tile * 64 + lane) * 8;
#pragma unroll
        for (int j = 0; j < 8; ++j) {
            int h = h0 + j;
            float v = (h < HH && k < HH) ? w_edge[h * HH + k] : 0.f;
            w_hi[base + j] = (_Float16)v;
        }
    } else {
        tile -= NKK * NCTE;
        const int kk = tile / NCT, ct = tile % NCT;
        const int h0 = kk * 32 + (lane >> 4) * 8;
        const int k  = ct * 16 + (lane & 15);
        const size_t base = ((size_t)tile * 64 + lane) * 8;
#pragma unroll
        for (int j = 0; j < 8; ++j) {
            int h = h0 + j;
            float v = (h < PP * HH && k < HH) ? w_np[(size_t)h * HH + k] : 0.f;
            w2_hi[base + j] = (_Float16)v;
        }
    }
}

// ---------------------------------------------------------------------------
// FUSED edge + node kernel — ROUND-15 BODY EXACTLY (best: 82.3 us total).
// Round 17's atomic-fenced in-kernel final cost 2x (device-scope acq/rel
// poisoned the memory path: HBM 886->465 GB/s) — reverted; final_kernel
// stays a separate dispatch. Edge = round-12 structure (single-buffer B
// staging, 32 rows/wave, ct-pair chains); node = round-10 structure.
// ---------------------------------------------------------------------------
extern "C" __global__ __launch_bounds__(256)
void fused_kernel(const float* __restrict__ edge_attr,
                  const float* __restrict__ node_attr,
                  const float* __restrict__ instr,
                  const float* __restrict__ dist,
                  const float* __restrict__ sim,
                  const float* __restrict__ node_mask,
                  const _Float16* __restrict__ w_hi,
                  const _Float16* __restrict__ w2_hi,
                  const float* __restrict__ w_rel,
                  const float* __restrict__ w_state,
                  float* __restrict__ rel_logits,
                  float* __restrict__ state_logits)
{
    __shared__ __align__(16) _Float16 Bs[2 * NKK * 512];  // edge: one ct-pair
    __shared__ float redE[2][NN];
    __shared__ float redN[4][16];
    const int tid  = (int)threadIdx.x;
    const int wv   = tid >> 6;
    const int lane = tid & 63;
    const int lrow = lane & 15;
    const int lgrp = lane >> 4;

    if ((int)blockIdx.x < NODE_BLOCKS) {
        // =================== NODE PATH (round-10 body) ====================
        const int bid = (int)blockIdx.x;
        const int b   = bid >> 2;
        const int nt  = bid & 3;

        const float* arow = node_attr
            + (size_t)(b * NN + nt * 16 + lrow) * (PP * HH);
        float sm[PP];
#pragma unroll
        for (int p = 0; p < PP; ++p) sm[p] = sim[b * PP + p];

        const f16x8* WH = reinterpret_cast<const f16x8*>(w2_hi);

        f32x4 acc[5] = {{0.f,0.f,0.f,0.f},{0.f,0.f,0.f,0.f},{0.f,0.f,0.f,0.f},
                        {0.f,0.f,0.f,0.f},{0.f,0.f,0.f,0.f}};

#pragma unroll 1
        for (int ch = 0; ch < 4; ++ch) {
            f16x8 a_h[CHK];
#pragma unroll
            for (int q = 0; q < CHK; ++q) {
                const int kk = ch * CHK + q;
                const int h0 = kk * 32 + lgrp * 8;
                float v[8];
                if (kk < NKK2 && h0 + 7 < PP * HH) {
                    f32x4 p0 = *reinterpret_cast<const f32x4*>(arow + h0);
                    f32x4 p1 = *reinterpret_cast<const f32x4*>(arow + h0 + 4);
                    v[0] = p0[0]; v[1] = p0[1]; v[2] = p0[2]; v[3] = p0[3];
                    v[4] = p1[0]; v[5] = p1[1]; v[6] = p1[2]; v[7] = p1[3];
                } else {
#pragma unroll
                    for (int j = 0; j < 8; ++j)
                        v[j] = (kk < NKK2 && h0 + j < PP * HH) ? arow[h0 + j] : 0.f;
                }
#pragma unroll
                for (int j = 0; j < 8; ++j) {
                    const int h = h0 + j;
                    const int p = (h < PP * HH) ? (h / HH) : 0;
                    a_h[q][j] = (_Float16)(v[j] * sm[p]);
                }
            }
#pragma unroll
            for (int q = 0; q < CHK; ++q) {
                const int kk = ch * CHK + q;
                if (kk < NKK2) {
#pragma unroll
                    for (int c = 0; c < 5; ++c) {
                        const int ct = wv + 4 * c;
                        if (ct < NCT) {
                            f16x8 bh = WH[(kk * NCT + ct) * 64 + lane];
                            acc[c] = __builtin_amdgcn_mfma_f32_16x16x32_f16(a_h[q], bh, acc[c], 0, 0, 0);
                        }
                    }
                }
            }
        }

        float rs0 = 0.f, rs1 = 0.f, rs2 = 0.f, rs3 = 0.f;
#pragma unroll
        for (int c = 0; c < 5; ++c) {
            const int ct = wv + 4 * c;
            if (ct < NCT) {
                const int k  = ct * 16 + lrow;
                const bool ok = k < HH;
                const int kc = ok ? k : (HH - 1);
                const float iv  = instr[b * HH + kc];
                const float wsv = ok ? w_state[kc] : 0.f;
                rs0 += eluf(acc[c][0] * iv) * wsv;
                rs1 += eluf(acc[c][1] * iv) * wsv;
                rs2 += eluf(acc[c][2] * iv) * wsv;
                rs3 += eluf(acc[c][3] * iv) * wsv;
            }
        }
#pragma unroll
        for (int msk = 1; msk < 16; msk <<= 1) {
            rs0 += __shfl_xor(rs0, msk);
            rs1 += __shfl_xor(rs1, msk);
            rs2 += __shfl_xor(rs2, msk);
            rs3 += __shfl_xor(rs3, msk);
        }
        if (lrow == 0) {
            redN[wv][lgrp * 4 + 0] = rs0;
            redN[wv][lgrp * 4 + 1] = rs1;
            redN[wv][lgrp * 4 + 2] = rs2;
            redN[wv][lgrp * 4 + 3] = rs3;
        }
        __syncthreads();
        if (tid < 16) {
            const int n = nt * 16 + tid;
            float v = redN[0][tid] + redN[1][tid] + redN[2][tid] + redN[3][tid];
            state_logits[b * NN + n] = v + node_mask[b * NN + n];
        }
        return;
    }

    // ===================== EDGE PATH (round-12 body) ======================
    const int ebid = (int)blockIdx.x - NODE_BLOCKS;
    const int b    = ebid / (NN / 2);
    const int mp   = ebid % (NN / 2);
    const int m0   = 2 * mp;
    const int mi   = wv >> 1;         // which m of the pair
    const int rh   = wv & 1;          // row-half (32 rows) within that m

    // ---- A fragments (fp16) for TWO 16-row sets, read-once from global ----
    const float* abase = edge_attr
        + (size_t)((b * NN + m0 + mi) * NN + rh * 32 + lrow) * HH;
    f16x8 aA[NKK], aB[NKK];
#pragma unroll
    for (int s = 0; s < 2; ++s) {
        const float* arow = abase + (size_t)(s * 16) * HH;
#pragma unroll
        for (int kk = 0; kk < NKK; ++kk) {
            const int h0 = kk * 32 + lgrp * 8;
            float v[8];
            if (h0 + 7 < HH) {
                f32x4 p0 = *reinterpret_cast<const f32x4*>(arow + h0);
                f32x4 p1 = *reinterpret_cast<const f32x4*>(arow + h0 + 4);
                v[0] = p0[0]; v[1] = p0[1]; v[2] = p0[2]; v[3] = p0[3];
                v[4] = p1[0]; v[5] = p1[1]; v[6] = p1[2]; v[7] = p1[3];
            } else {
#pragma unroll
                for (int j = 0; j < 8; ++j)
                    v[j] = (h0 + j < HH) ? arow[h0 + j] : 0.f;
            }
            if (s == 0) {
#pragma unroll
                for (int j = 0; j < 8; ++j) aA[kk][j] = (_Float16)v[j];
            } else {
#pragma unroll
                for (int j = 0; j < 8; ++j) aB[kk][j] = (_Float16)v[j];
            }
        }
    }

    const f16x8* WH = reinterpret_cast<const f16x8*>(w_hi);
    const int binst = b * HH;

    // ---- staging ownership: 20 pair-tiles over 4 waves (5 each),
    // decoded ONCE; pointers advance by constant 128 f16x8 per pair.
    const int t0 = wv * 5;
    const f16x8* gp[5];
    int ldst[5];
#pragma unroll
    for (int i = 0; i < 5; ++i) {
        int t  = t0 + i;
        int c  = (t >= NKK) ? 1 : 0;
        int kk = t - c * NKK;
        gp[i]   = WH + ((size_t)kk * NCTE + c) * 64 + lane;
        ldst[i] = (c * NKK + kk) * 512 + lane * 8;
    }

    f16x8 st[5];
#pragma unroll
    for (int i = 0; i < 5; ++i) { st[i] = gp[i][0]; gp[i] += 128; }

    float rsA0 = 0.f, rsA1 = 0.f, rsA2 = 0.f, rsA3 = 0.f;
    float rsB0 = 0.f, rsB1 = 0.f, rsB2 = 0.f, rsB3 = 0.f;

#pragma unroll 1
    for (int p = 0; p < NPAIR; ++p) {
        // write this pair's staged registers into LDS
#pragma unroll
        for (int i = 0; i < 5; ++i)
            *reinterpret_cast<f16x8*>(&Bs[ldst[i]]) = st[i];
        __syncthreads();

        // issue next pair's loads early (consumed after next barrier)
        if (p + 1 < NPAIR) {
#pragma unroll
            for (int i = 0; i < 5; ++i) { st[i] = gp[i][0]; gp[i] += 128; }
        }

        // compute pair from LDS: 4 independent acc chains (rowset x ct)
        f32x4 accA0 = {0.f, 0.f, 0.f, 0.f};
        f32x4 accA1 = {0.f, 0.f, 0.f, 0.f};
        f32x4 accB0 = {0.f, 0.f, 0.f, 0.f};
        f32x4 accB1 = {0.f, 0.f, 0.f, 0.f};
        const _Float16* bsc = &Bs[lane * 8];
#pragma unroll
        for (int kk = 0; kk < NKK; ++kk) {
            f16x8 b0 = *reinterpret_cast<const f16x8*>(bsc + kk * 512);
            f16x8 b1 = *reinterpret_cast<const f16x8*>(bsc + (NKK + kk) * 512);
            accA0 = __builtin_amdgcn_mfma_f32_16x16x32_f16(aA[kk], b0, accA0, 0, 0, 0);
            accB0 = __builtin_amdgcn_mfma_f32_16x16x32_f16(aB[kk], b0, accB0, 0, 0, 0);
            accA1 = __builtin_amdgcn_mfma_f32_16x16x32_f16(aA[kk], b1, accA1, 0, 0, 0);
            accB1 = __builtin_amdgcn_mfma_f32_16x16x32_f16(aB[kk], b1, accB1, 0, 0, 0);
        }

        // fused epilogue for both ct's of the pair, both rowsets
#pragma unroll
        for (int c = 0; c < 2; ++c) {
            const int k  = (2 * p + c) * 16 + lrow;
            const bool ok = k < HH;
            const int kc = ok ? k : (HH - 1);
            const float iv = instr[binst + kc];
            const float wr = ok ? w_rel[kc] : 0.f;
            const f32x4 aAc = c ? accA1 : accA0;
            const f32x4 aBc = c ? accB1 : accB0;
            rsA0 += eluf(aAc[0] * iv) * wr;
            rsA1 += eluf(aAc[1] * iv) * wr;
            rsA2 += eluf(aAc[2] * iv) * wr;
            rsA3 += eluf(aAc[3] * iv) * wr;
            rsB0 += eluf(aBc[0] * iv) * wr;
            rsB1 += eluf(aBc[1] * iv) * wr;
            rsB2 += eluf(aBc[2] * iv) * wr;
            rsB3 += eluf(aBc[3] * iv) * wr;
        }

        __syncthreads();   // all waves done reading Bs before next overwrite
    }

    // reduce over the 16 lanes sharing the same C-rows (masks 1,2,4,8)
#pragma unroll
    for (int msk = 1; msk < 16; msk <<= 1) {
        rsA0 += __shfl_xor(rsA0, msk);
        rsA1 += __shfl_xor(rsA1, msk);
        rsA2 += __shfl_xor(rsA2, msk);
        rsA3 += __shfl_xor(rsA3, msk);
        rsB0 += __shfl_xor(rsB0, msk);
        rsB1 += __shfl_xor(rsB1, msk);
        rsB2 += __shfl_xor(rsB2, msk);
        rsB3 += __shfl_xor(rsB3, msk);
    }
    if (lrow == 0) {
        const int r0 = rh * 32 + lgrp * 4;
        redE[mi][r0 + 0]      = rsA0;
        redE[mi][r0 + 1]      = rsA1;
        redE[mi][r0 + 2]      = rsA2;
        redE[mi][r0 + 3]      = rsA3;
        redE[mi][r0 + 16 + 0] = rsB0;
        redE[mi][r0 + 16 + 1] = rsB1;
        redE[mi][r0 + 16 + 2] = rsB2;
        redE[mi][r0 + 16 + 3] = rsB3;
    }
    __syncthreads();
    if (tid < 128) {
        const int mm = tid >> 6;
        const int ln = tid & 63;
        float v = redE[mm][ln] * dist[b * NN + ln];
#pragma unroll
        for (int msk = 1; msk < 64; msk <<= 1) v += __shfl_xor(v, msk);
        if (ln == 0)
            rel_logits[b * NN + m0 + mm] = v + node_mask[b * NN + m0 + mm];
    }
}

// ---------------------------------------------------------------------------
// Final: softmax both logit sets over n (one wave per b) and blend.
// ---------------------------------------------------------------------------
extern "C" __global__ __launch_bounds__(64)
void final_kernel(const float* __restrict__ rel_logits,
                  const float* __restrict__ state_logits,
                  const float* __restrict__ rel_sim,
                  float* __restrict__ out)
{
    const int b = (int)blockIdx.x;
    const int n = (int)threadIdx.x;
    float sl = state_logits[b * NN + n];
    float rl = rel_logits[b * NN + n];

    float ms = sl, mr = rl;
#pragma unroll
    for (int msk = 1; msk < 64; msk <<= 1) {
        ms = fmaxf(ms, __shfl_xor(ms, msk));
        mr = fmaxf(mr, __shfl_xor(mr, msk));
    }
    float es = __expf(sl - ms);
    float er = __expf(rl - mr);
    float ss = es, sr = er;
#pragma unroll
    for (int msk = 1; msk < 64; msk <<= 1) {
        ss += __shfl_xor(ss, msk);
        sr += __shfl_xor(sr, msk);
    }
    float rr = rel_sim[b];
    out[b * NN + n] = rr * (er / sr) + (1.f - rr) * (es / ss);
}

extern "C" void kernel_launch(void* const* d_in, const int* in_sizes, int n_in,
                              void* d_out, int out_size, void* d_ws, size_t ws_size,
                              hipStream_t stream) {
    const float* node_attr    = (const float*)d_in[0];
    const float* edge_attr    = (const float*)d_in[1];
    const float* instruction  = (const float*)d_in[2];
    const float* distribution = (const float*)d_in[3];
    const float* node_sim     = (const float*)d_in[4];
    const float* rel_sim      = (const float*)d_in[5];
    const float* node_mask    = (const float*)d_in[6];
    const float* w_np         = (const float*)d_in[7];
    const float* w_edge       = (const float*)d_in[8];
    const float* w_state      = (const float*)d_in[9];
    const float* w_rel        = (const float*)d_in[10];
    float* out = (float*)d_out;

    // workspace layout
    float* rel_ws   = (float*)d_ws;                           // [2048] f32
    float* state_ws = rel_ws + BB * NN;                       // [2048] f32
    char*  wsb      = (char*)d_ws;
    const size_t edge_frag = (size_t)NKK * NCTE * 64 * 8 * 2;  // 204,800 B
    _Float16* w_hi  = (_Float16*)(wsb + 16384);
    _Float16* w2_hi = (_Float16*)(wsb + 16384 + edge_frag);

    wprep_kernel<<<dim3((NTILES + 3) / 4), dim3(256), 0, stream>>>(
        w_edge, w_np, w_hi, w2_hi);

    fused_kernel<<<dim3(NODE_BLOCKS + EDGE_BLOCKS), dim3(256), 0, stream>>>(
        edge_attr, node_attr, instruction, distribution, node_sim, node_mask,
        w_hi, w2_hi, w_rel, w_state, rel_ws, state_ws);

    final_kernel<<<dim3(BB), dim3(64), 0, stream>>>(
        rel_ws, state_ws, rel_sim, out);
}